// Round 17
// baseline (222.820 us; speedup 1.0000x reference)
//
#include <hip/hip_runtime.h>
#include <stdint.h>

// Problem constants
#define BB 64
#define VV 2000
#define DD 16
#define CI 64
#define CO 64

// ---- ws layout ----
// dword offsets (fp32 region)
#define WS_INV_DW   0
#define WS_Z_DW     1024                    // float2[16][4096]
#define WS_BIAS_DW  132096                  // fp32 [2000][128]  (idx = 2*o+half)
// byte offsets (bf16 regions), all 16B-aligned
#define WS_NE_B     1552384UL               // bf16 [2048][64]  (hi/lo split ne)
#define WS_RHS_B    1814528UL               // bf16 [16384][64] compact RHS
#define WS_U_B      4960256UL               // bf16 [2000][3][64][64] compact U
#define WS_W_B      54112256UL              // bf16 [2000][4][64][64] compact W
// R8: ZP (z partials) and NP (norm1 partials) in DEDICATED space at 128 MiB.
#define WS_ZP_DW    33554432                // byte 128 MiB; 8.4 MB
#define WS_NP_DW    (WS_ZP_DW + 2097152)    // 100 blocks x 512 floats

typedef __attribute__((ext_vector_type(8))) short short8;
typedef __attribute__((ext_vector_type(4))) float f32x4;

__device__ __forceinline__ uint32_t f2bf(float f) {
  uint32_t u = __float_as_uint(f);
  return (u + 0x7FFFu + ((u >> 16) & 1u)) >> 16;   // RNE
}

// Direct global->LDS DMA, 16B per lane. LDS dest = wave-uniform base +
// lane*16; global src is per-lane. No VGPR round trip, no scratch.
__device__ __forceinline__ void gload_lds16(const void* g, void* l) {
  __builtin_amdgcn_global_load_lds(
      (const __attribute__((address_space(1))) uint32_t*)g,
      (__attribute__((address_space(3))) uint32_t*)l, 16, 0, 0);
}

// ---------------------------------------------------------------------------
// Component bodies, fused into k_front / k_mid by blockIdx range.
//   k_front: {z (+U[c=0] write), rhs, norm1, bias, ne}   (independent)
//   k_mid:   {wgemm, zred, norm2}        (all need only k_front)
//   k_u:     needs Z + INV (k_mid); writes U[c=1,2] only
//   k_final: needs W (k_mid) + U (k_front c=0, k_u c=1,2) + bias (k_front)
// ---------------------------------------------------------------------------

// z: Z partials. 1024 virtual blocks = (b:64)x(chunk:16).
__device__ __forceinline__ void body_z(int bz, int t,
    const float* __restrict__ x, const float* __restrict__ ne_re,
    const float* __restrict__ ne_im, float* __restrict__ ws) {
  int b = bz >> 4, c = bz & 15;
  int lane = t & 63;
  int w = __builtin_amdgcn_readfirstlane(t >> 6);   // wave-uniform in SGPR
  __shared__ __align__(16) float smem[8192];        // 32 KB: x-tile, then sred

  int vbase = c * 125;

  // stage x[b, vbase..vbase+125, :] = 32000 B contiguous into LDS via DMA.
  {
    const float4* xg = (const float4*)(x + ((size_t)b * VV + vbase) * CI);
    int wb = t & 192;                               // w*64, uniform per wave
    #pragma unroll
    for (int p = 0; p < 8; ++p) {
      int idx = p * 256 + t;
      if (idx < 2000)
        gload_lds16(xg + idx, &smem[(p * 256 + wb) * 4]);
    }
  }
  __syncthreads();                                  // compiler drains vmcnt

  float zr[DD], zi[DD];
  #pragma unroll
  for (int d = 0; d < DD; ++d) { zr[d] = 0.f; zi[d] = 0.f; }

  uint16_t* Ux = (uint16_t*)((char*)ws + WS_U_B);
  int bkey = b & 7;
  int pos = (((lane >> 3) ^ bkey) & 7)*8 + (lane & 7);

  int lv0 = (w * 125) >> 2;                         // uniform bounds (SGPR)
  int lv1 = ((w + 1) * 125) >> 2;
  #pragma unroll 4
  for (int lv = lv0; lv < lv1; ++lv) {
    float xv = smem[lv * 64 + lane];                // stride-1: conflict-free
    int v = vbase + lv;                             // uniform -> s_load ne
    Ux[(size_t)v*12288 + b*64 + pos] = (uint16_t)f2bf(xv);  // U[c=0]
    #pragma unroll
    for (int d = 0; d < DD; ++d) {
      zr[d] += ne_re[v*DD + d] * xv;
      zi[d] -= ne_im[v*DD + d] * xv;
    }
  }
  __syncthreads();                                  // all waves done with x-tile

  #pragma unroll
  for (int d = 0; d < DD; ++d) {
    smem[w*2048 + d*128 + lane*2 + 0] = zr[d];
    smem[w*2048 + d*128 + lane*2 + 1] = zi[d];
  }
  __syncthreads();
  float* ZP = ws + WS_ZP_DW;
  #pragma unroll
  for (int k = 0; k < 8; ++k) {
    int j = t + k*256;
    float s = smem[j] + smem[2048 + j] + smem[4096 + j] + smem[6144 + j];
    int d = j >> 7, r = j & 127;
    ZP[(size_t)c*131072 + d*8192 + b*128 + r] = s;
  }
}

// ne: NE[u][col] bf16, col = h*32 + d*2 + p; h=0: bf16(ne), h=1: bf16(ne - hi)
__device__ __forceinline__ void body_ne(int bx, int t,
    const float* __restrict__ ne_re, const float* __restrict__ ne_im,
    float* __restrict__ ws) {
  int gid = bx * 256 + t;                     // 512 blocks -> 131072
  int u = gid >> 6, col = gid & 63;
  int h = col >> 5, kk = col & 31, d = kk >> 1, p = kk & 1;
  float v = 0.f;
  if (u < VV) v = p ? ne_im[u*DD + d] : ne_re[u*DD + d];
  uint32_t hi = f2bf(v);
  uint32_t ov = h ? f2bf(v - __uint_as_float(hi << 16)) : hi;
  ((uint16_t*)((char*)ws + WS_NE_B))[gid] = (uint16_t)ov;
}

// rhs: compact RHS[n'][k]. 256 blocks = (c:4)x(ig4:16)x(dq:4).
__device__ __forceinline__ void body_rhs(int bx, int t,
    const float* __restrict__ w_re, const float* __restrict__ w_im,
    float* __restrict__ ws) {
  int c = bx >> 6, sub = bx & 63;
  int ig4 = sub & 15, dq = sub >> 4;
  int o = t & 63, il = t >> 6;
  int i = ig4*4 + il;
  int cb = c >> 1;                     // 0: wA = w0-w2, 1: wB = w1+2w2
  int imf = c & 1;                     // odd comp: (Im, Re); even: (Re, -Im)

  uint32_t row32[4];
  #pragma unroll
  for (int d4 = 0; d4 < 4; ++d4) {
    int d = dq*4 + d4;
    int b0 = (d*192 + i)*64 + o;       // w[d,kc,i,o]: d stride 12288, kc 4096
    float vre, vim;
    if (cb == 0) {
      vre = w_re[b0] - w_re[b0 + 8192];
      vim = w_im[b0] - w_im[b0 + 8192];
    } else {
      vre = w_re[b0 + 4096] + 2.f*w_re[b0 + 8192];
      vim = w_im[b0 + 4096] + 2.f*w_im[b0 + 8192];
    }
    float q0 = imf ? vim : vre;
    float q1 = imf ? vre : -vim;
    row32[d4] = f2bf(q0) | (f2bf(q1) << 16);
  }
  int s = ((i >> 3) ^ (o & 7)) & 7;
  int n = c*4096 + o*64 + s*8 + (i & 7);
  uint4* dst = (uint4*)((uint16_t*)((char*)ws + WS_RHS_B) + (size_t)n*64);
  uint4 qv = make_uint4(row32[0], row32[1], row32[2], row32[3]);
  dst[dq]     = qv;   // h=0
  dst[dq + 4] = qv;   // h=1 duplicate (hi/lo ne split reconstructs fp32)
}

// norm1: partial Gram. 100 virtual blocks x 20 v. Partials to NP.
__device__ __forceinline__ void body_norm1(int bx, int t,
    const float* __restrict__ ne_re, const float* __restrict__ ne_im,
    float* __restrict__ ws) {
  int d = t >> 4, e = t & 15;
  int v0 = bx * 20;
  float gr = 0.f, gi = 0.f;
  #pragma unroll 4
  for (int v = v0; v < v0 + 20; ++v) {
    float ar = ne_re[v*DD + d], ai = ne_im[v*DD + d];
    float br = ne_re[v*DD + e], bi = ne_im[v*DD + e];
    gr += ar*br + ai*bi;
    gi += ar*bi - ai*br;
  }
  float* NP = ws + WS_NP_DW;
  NP[bx*512 + 2*t]     = gr;
  NP[bx*512 + 2*t + 1] = gi;
}

// bias: bias2[u][2*o+half] fp32 (interleaved so k_final stores are linear)
__device__ __forceinline__ void body_bias(int bx, int t,
    const float* __restrict__ ne_re, const float* __restrict__ ne_im,
    const float* __restrict__ b_re, const float* __restrict__ b_im,
    float* __restrict__ ws) {
  int gid = bx * 256 + t;                     // 1000 blocks -> 256000
  int u = gid >> 7, idx = gid & 127;
  int o = idx >> 1, half = idx & 1;
  float acc = 0.f;
  #pragma unroll
  for (int d = 0; d < DD; ++d) {
    float nr = ne_re[u*DD + d], ni = ne_im[u*DD + d];
    float pr = b_re[d*CO + o],  pi = b_im[d*CO + o];
    acc += half ? (nr*pi + ni*pr) : (nr*pr - ni*pi);
  }
  ws[WS_BIAS_DW + gid] = acc;
}

// wgemm: W GEMM -> compact Wc[u][16384].
__device__ __forceinline__ void body_wgemm(int bx, int t, float* __restrict__ ws) {
  const uint16_t* NE  = (const uint16_t*)((char*)ws + WS_NE_B);
  const uint16_t* RHS = (const uint16_t*)((char*)ws + WS_RHS_B);
  uint32_t*       W   = (uint32_t*)((char*)ws + WS_W_B);
  int ut = bx & 31, nc = bx >> 5;
  int w = t >> 6, lane = t & 63;
  int n16 = lane & 15, quad = lane >> 4;
  short8 a[4][2];
  #pragma unroll
  for (int m = 0; m < 4; ++m) {
    int u = ut*64 + m*16 + n16;
    a[m][0] = *(const short8*)(NE + u*64 + quad*8);
    a[m][1] = *(const short8*)(NE + u*64 + 32 + quad*8);
  }
  int nbase = nc*1024 + w*256;
  #pragma unroll 2
  for (int pt = 0; pt < 8; ++pt) {
    int nb = nbase + pt*32;
    const uint16_t* r0 = RHS + (size_t)(nb + 2*n16 + 0)*64 + quad*8;
    const uint16_t* r1 = RHS + (size_t)(nb + 2*n16 + 1)*64 + quad*8;
    short8 b00 = *(const short8*)r0;
    short8 b01 = *(const short8*)(r0 + 32);
    short8 b10 = *(const short8*)r1;
    short8 b11 = *(const short8*)(r1 + 32);
    #pragma unroll
    for (int m = 0; m < 4; ++m) {
      f32x4 acc0 = (f32x4){0.f,0.f,0.f,0.f};
      f32x4 acc1 = (f32x4){0.f,0.f,0.f,0.f};
      acc0 = __builtin_amdgcn_mfma_f32_16x16x32_bf16(a[m][0], b00, acc0, 0, 0, 0);
      acc0 = __builtin_amdgcn_mfma_f32_16x16x32_bf16(a[m][1], b01, acc0, 0, 0, 0);
      acc1 = __builtin_amdgcn_mfma_f32_16x16x32_bf16(a[m][0], b10, acc1, 0, 0, 0);
      acc1 = __builtin_amdgcn_mfma_f32_16x16x32_bf16(a[m][1], b11, acc1, 0, 0, 0);
      #pragma unroll
      for (int r = 0; r < 4; ++r) {
        int u = ut*64 + m*16 + quad*4 + r;
        if (u < VV) {
          uint32_t pk = f2bf(acc0[r]) | (f2bf(acc1[r]) << 16);
          W[(size_t)u*8192 + (nb >> 1) + n16] = pk;
        }
      }
    }
  }
}

// zred: Z = sum over 16 chunks of ZP. 256 virtual blocks.
__device__ __forceinline__ void body_zred(int bx, int t, float* __restrict__ ws) {
  int g = bx * 256 + t;
  const float2* ZP2 = (const float2*)(ws + WS_ZP_DW);
  float2 acc = make_float2(0.f, 0.f);
  #pragma unroll
  for (int c = 0; c < 16; ++c) {
    float2 v = ZP2[(size_t)c*65536 + g];
    acc.x += v.x; acc.y += v.y;
  }
  ((float2*)(ws + WS_Z_DW))[g] = acc;
}

// norm2: reduce NP partials -> INV. 1 virtual block. 100 partials.
__device__ __forceinline__ void body_norm2(int t, float* __restrict__ ws) {
  const float* NP = ws + WS_NP_DW;
  float gr = 0.f, gi = 0.f;
  #pragma unroll
  for (int p = 0; p < 100; ++p) {
    gr += NP[p*512 + 2*t];
    gi += NP[p*512 + 2*t + 1];
  }
  __shared__ float red[256];
  red[t] = gr*gr + gi*gi;
  __syncthreads();
  for (int k = 128; k > 0; k >>= 1) {
    if (t < k) red[t] += red[t + k];
    __syncthreads();
  }
  if (t == 0) ws[WS_INV_DW] = 1.0f / sqrtf(red[0]);
}

// ---------------------------------------------------------------------------
// Fused dispatchers
// ---------------------------------------------------------------------------

// k_front: 2892 blocks, longest-per-block first:
//   z [0,1024) | rhs [1024,1280) | norm1 [1280,1380) |
//   bias [1380,2380) | ne [2380,2892)
__global__ void __launch_bounds__(256, 4)
k_front(const float* __restrict__ x, const float* __restrict__ ne_re,
        const float* __restrict__ ne_im, const float* __restrict__ w_re,
        const float* __restrict__ w_im, const float* __restrict__ b_re,
        const float* __restrict__ b_im, float* __restrict__ ws) {
  int bx = blockIdx.x, t = threadIdx.x;
  if (bx < 1024) {
    body_z(bx, t, x, ne_re, ne_im, ws);
  } else if (bx < 1280) {
    body_rhs(bx - 1024, t, w_re, w_im, ws);
  } else if (bx < 1380) {
    body_norm1(bx - 1280, t, ne_re, ne_im, ws);
  } else if (bx < 2380) {
    body_bias(bx - 1380, t, ne_re, ne_im, b_re, b_im, ws);
  } else {
    body_ne(bx - 2380, t, ne_re, ne_im, ws);
  }
}

// k_mid: 769 blocks. wgemm [0,512) | zred [512,768) | norm2 768.
__global__ void __launch_bounds__(256, 4)
k_mid(float* __restrict__ ws) {
  int bx = blockIdx.x, t = threadIdx.x;
  if (bx < 512) {
    body_wgemm(bx, t, ws);
  } else if (bx < 768) {
    body_zred(bx - 512, t, ws);
  } else {
    body_norm2(t, ws);
  }
}

// K7: y-only. compact U[u][1,2][64][64] (yr, yi; swizzle baked).
__global__ void __launch_bounds__(256, 4)
k_u(const float* __restrict__ x, const float* __restrict__ ne_re,
    const float* __restrict__ ne_im, float* __restrict__ ws) {
  (void)x;
  int ug = blockIdx.x, by = blockIdx.y;
  int t = threadIdx.x, q = t >> 6, i = t & 63;
  int b = by*4 + q;
  float invn = ws[WS_INV_DW];

  // Z loads (16 x 8B, cache-resident)
  const float* Z = ws + WS_Z_DW;
  float zr[DD], zi[DD];
  #pragma unroll
  for (int d = 0; d < DD; ++d) {
    const float* zp = Z + (size_t)(d*4096 + b*64 + i) * 2;
    zr[d] = zp[0]; zi[d] = zp[1];
  }

  __shared__ uint16_t sStage[128 * 64];       // rr = ul*8 + cc*4 + q
  int bkey = b & 7;
  int pos = (((i >> 3) ^ bkey) & 7)*8 + (i & 7);

  // y compute, fully unrolled, split accumulators
  #pragma unroll
  for (int ul = 0; ul < 16; ++ul) {
    int u = ug*16 + ul;
    float yra = 0.f, yrb = 0.f, yia = 0.f, yib = 0.f;
    #pragma unroll
    for (int d = 0; d < DD; ++d) {
      float nr = ne_re[u*DD + d], ni = ne_im[u*DD + d];
      yra += nr*zr[d]; yrb += ni*zi[d];
      yia += nr*zi[d]; yib += ni*zr[d];
    }
    float yr = yra - yrb, yi = yia + yib;
    sStage[(ul*8 + 0 + q)*64 + pos] = (uint16_t)f2bf(yr * invn);
    sStage[(ul*8 + 4 + q)*64 + pos] = (uint16_t)f2bf(yi * invn);
  }
  __syncthreads();
  // flush: 128 rows x 128B, 32 rows per pass (8 lanes/row), 4 passes
  uint16_t* U = (uint16_t*)((char*)ws + WS_U_B);
  const uint4* sv = (const uint4*)sStage;
  #pragma unroll
  for (int pass = 0; pass < 4; ++pass) {
    int rr = pass*32 + (t >> 3), l8 = t & 7;
    int ul = rr >> 3, rem = rr & 7;
    int cc = rem >> 2, qq = rem & 3;             // cc: 0=yr->c=1, 1=yi->c=2
    uint4 v = sv[rr*8 + l8];
    *(uint4*)(U + (size_t)(ug*16 + ul)*12288 + (1+cc)*4096 + (by*4 + qq)*64 + l8*8) = v;
  }
}

// K8: per-node MFMA from compact W,U.
// R15: two-phase LDS (40 KB instead of 70 KB) -> 3 blocks/CU (was 2).
// k_final is streaming (57 KB loads/block, 24 MFMA ~ 200cyc): the old 70 KB
// LDS capped occupancy and the load->barrier->compute structure drained the
// pipeline per block. Phases partition exactly by cb:
//   A: W c=0,1 (rows 0..127) + U cb=0 (rows 128..191)       [ks 0,1]
//   B: W c=2,3 (rows 0..127) + U cb=1,2 (rows 128..255)     [ks 2..5]
// All 7 global loads issued up-front to registers (one latency exposure);
// accumulators persist across phases. Same math, same swizzle formulas.
#define LP 80           // LDS row pitch (elems)
#define CSTRIDE 5120    // 64*LP: comp stride (elems)
__global__ void __launch_bounds__(512, 6)
k_final(const float* __restrict__ ws, float* __restrict__ out) {
  int u = blockIdx.x, t = threadIdx.x;
  __shared__ __align__(16) uint16_t sB[256 * LP];      // 40960 B, dual-phase
  const uint4* Wg = (const uint4*)((const char*)ws + WS_W_B + (size_t)u*32768);
  const uint4* Ug = (const uint4*)((const char*)ws + WS_U_B + (size_t)u*24576);

  // prefetch all 7 x 16B chunks (independent loads, all in flight)
  uint4 rW[4], rU[3];
  #pragma unroll
  for (int j = 0; j < 4; ++j) rW[j] = Wg[j*512 + t];
  #pragma unroll
  for (int j = 0; j < 3; ++j) rU[j] = Ug[j*512 + t];

  int w = t >> 6, lane = t & 63;
  int n16 = lane & 15, quad = lane >> 4;
  int o = w*8 + (n16 >> 1), half = n16 & 1;
  int okey = o & 7;
  uint32_t sgnmask = half ? 0u : 0x80008000u;  // negate Bi for re-half at cb=2
  f32x4 acc[4];
  #pragma unroll
  for (int m = 0; m < 4; ++m) acc[m] = (f32x4){0.f,0.f,0.f,0.f};

  // ---- Phase A stage: W c=0,1 -> rows 0..127; U cb=0 -> rows 128..191 ----
  #pragma unroll
  for (int j = 0; j < 2; ++j) {
    int idx = j*512 + t;                       // rows 0..127
    *(uint4*)&sB[(idx >> 3)*LP + (idx & 7)*8] = rW[j];
  }
  {
    int idx = t;                               // U rows 0..63 -> LDS 128..191
    *(uint4*)&sB[(128 + (idx >> 3))*LP + (idx & 7)*8] = rU[0];
  }
  __syncthreads();

  // ---- Phase A compute: ks = 0,1 (cb=0, c=half) ----
  #pragma unroll
  for (int ks = 0; ks < 2; ++ks) {
    int i8 = ks*4 + quad;
    int c  = half;
    int slot = (i8 ^ okey) & 7;
    short8 bfrag = *(const short8*)&sB[c*CSTRIDE + o*LP + slot*8];
    #pragma unroll
    for (int m = 0; m < 4; ++m) {
      int b = m*16 + n16;
      int aslot = (i8 ^ (b & 7)) & 7;
      short8 afrag = *(const short8*)&sB[(128 + b)*LP + aslot*8];
      acc[m] = __builtin_amdgcn_mfma_f32_16x16x32_bf16(afrag, bfrag, acc[m], 0, 0, 0);
    }
  }
  __syncthreads();

  // ---- Phase B stage: W c=2,3 -> rows 0..127; U cb=1,2 -> rows 128..255 ----
  #pragma unroll
  for (int j = 2; j < 4; ++j) {
    int idx = j*512 + t;
    int row = (idx >> 3) - 128;                // c=2,3 -> rows 0..127
    *(uint4*)&sB[row*LP + (idx & 7)*8] = rW[j];
  }
  #pragma unroll
  for (int j = 1; j < 3; ++j) {
    int idx = j*512 + t;
    int row = (idx >> 3) - 64;                 // cb=1,2 -> rows 0..127
    *(uint4*)&sB[(128 + row)*LP + (idx & 7)*8] = rU[j];
  }
  __syncthreads();

  // ---- Phase B compute: ks = 2..5 (cb=1,2) ----
  #pragma unroll
  for (int ks = 2; ks < 6; ++ks) {
    int cb = ks >> 1;                          // 1,1,2,2
    int i8 = (ks & 1)*4 + quad;
    int c  = (cb == 1) ? 2 + half : 3 - half;  // in {2,3}
    int c2 = c - 2;
    int slot = (i8 ^ okey) & 7;
    short8 bfrag = *(const short8*)&sB[c2*CSTRIDE + o*LP + slot*8];
    if (cb == 2) {
      uint32_t* bu = (uint32_t*)&bfrag;
      #pragma unroll
      for (int jj = 0; jj < 4; ++jj) bu[jj] ^= sgnmask;
    }
    int cbl = cb - 1;                          // 0,1
    #pragma unroll
    for (int m = 0; m < 4; ++m) {
      int b = m*16 + n16;
      int aslot = (i8 ^ (b & 7)) & 7;
      short8 afrag = *(const short8*)&sB[(128 + cbl*64 + b)*LP + aslot*8];
      acc[m] = __builtin_amdgcn_mfma_f32_16x16x32_bf16(afrag, bfrag, acc[m], 0, 0, 0);
    }
  }

  float bias = ws[WS_BIAS_DW + u*128 + w*16 + n16];
  #pragma unroll
  for (int m = 0; m < 4; ++m) {
    #pragma unroll
    for (int r = 0; r < 4; ++r) {
      int b = m*16 + quad*4 + r;
      out[((size_t)b*VV + u)*128 + w*16 + n16] = acc[m][r] + bias;
    }
  }
}

// ---------------------------------------------------------------------------
extern "C" void kernel_launch(void* const* d_in, const int* in_sizes, int n_in,
                              void* d_out, int out_size, void* d_ws, size_t ws_size,
                              hipStream_t stream) {
  (void)in_sizes; (void)n_in; (void)out_size; (void)ws_size;
  const float* x     = (const float*)d_in[0];
  const float* ne_re = (const float*)d_in[1];
  const float* ne_im = (const float*)d_in[2];
  const float* w_re  = (const float*)d_in[3];
  const float* w_im  = (const float*)d_in[4];
  const float* b_re  = (const float*)d_in[5];
  const float* b_im  = (const float*)d_in[6];
  float* out = (float*)d_out;
  float* ws  = (float*)d_ws;

  k_front<<<dim3(2892),    dim3(256), 0, stream>>>(x, ne_re, ne_im, w_re, w_im,
                                                   b_re, b_im, ws);
  k_mid  <<<dim3(769),     dim3(256), 0, stream>>>(ws);
  k_u    <<<dim3(125, 16), dim3(256), 0, stream>>>(x, ne_re, ne_im, ws);
  k_final<<<dim3(VV),      dim3(512), 0, stream>>>(ws, out);
}

// Round 20
// 221.894 us; speedup vs baseline: 1.0042x; 1.0042x over previous
//
#include <hip/hip_runtime.h>
#include <stdint.h>

// Problem constants
#define BB 64
#define VV 2000
#define DD 16
#define CI 64
#define CO 64

// ---- ws layout ----
// dword offsets (fp32 region)
#define WS_INV_DW   0
#define WS_Z_DW     1024                    // float2[16][4096]
#define WS_BIAS_DW  132096                  // fp32 [2000][128]  (idx = 2*o+half)
// byte offsets (bf16 regions), all 16B-aligned
#define WS_NE_B     1552384UL               // bf16 [2048][64]  (hi/lo split ne)
#define WS_RHS_B    1814528UL               // bf16 [16384][64] compact RHS
#define WS_U_B      4960256UL               // bf16 [2000][3][64][64] compact U
#define WS_W_B      54112256UL              // bf16 [2000][4][64][64] compact W
// R8: ZP (z partials) and NP (norm1 partials) in DEDICATED space at 128 MiB.
#define WS_ZP_DW    33554432                // byte 128 MiB; 8.4 MB
#define WS_NP_DW    (WS_ZP_DW + 2097152)    // 100 blocks x 512 floats

typedef __attribute__((ext_vector_type(8))) short short8;
typedef __attribute__((ext_vector_type(4))) float f32x4;

__device__ __forceinline__ uint32_t f2bf(float f) {
  uint32_t u = __float_as_uint(f);
  return (u + 0x7FFFu + ((u >> 16) & 1u)) >> 16;   // RNE
}

// Direct global->LDS DMA, 16B per lane. LDS dest = wave-uniform base +
// lane*16; global src is per-lane. No VGPR round trip, no scratch.
__device__ __forceinline__ void gload_lds16(const void* g, void* l) {
  __builtin_amdgcn_global_load_lds(
      (const __attribute__((address_space(1))) uint32_t*)g,
      (__attribute__((address_space(3))) uint32_t*)l, 16, 0, 0);
}

// ---------------------------------------------------------------------------
// Component bodies, fused into k_front / k_mid by blockIdx range.
//   k_front: {z (+U[c=0] write), rhs, norm1, bias, ne}   (independent)
//   k_mid:   {wgemm, zred, norm2}        (all need only k_front)
//   k_u:     needs Z + INV (k_mid); writes U[c=1,2] only
//   k_final: needs W (k_mid) + U (k_front c=0, k_u c=1,2) + bias (k_front)
// ---------------------------------------------------------------------------

// z: Z partials. 1024 virtual blocks = (b:64)x(chunk:16).
__device__ __forceinline__ void body_z(int bz, int t,
    const float* __restrict__ x, const float* __restrict__ ne_re,
    const float* __restrict__ ne_im, float* __restrict__ ws) {
  int b = bz >> 4, c = bz & 15;
  int lane = t & 63;
  int w = __builtin_amdgcn_readfirstlane(t >> 6);   // wave-uniform in SGPR
  __shared__ __align__(16) float smem[8192];        // 32 KB: x-tile, then sred

  int vbase = c * 125;

  // stage x[b, vbase..vbase+125, :] = 32000 B contiguous into LDS via DMA.
  {
    const float4* xg = (const float4*)(x + ((size_t)b * VV + vbase) * CI);
    int wb = t & 192;                               // w*64, uniform per wave
    #pragma unroll
    for (int p = 0; p < 8; ++p) {
      int idx = p * 256 + t;
      if (idx < 2000)
        gload_lds16(xg + idx, &smem[(p * 256 + wb) * 4]);
    }
  }
  __syncthreads();                                  // compiler drains vmcnt

  float zr[DD], zi[DD];
  #pragma unroll
  for (int d = 0; d < DD; ++d) { zr[d] = 0.f; zi[d] = 0.f; }

  uint16_t* Ux = (uint16_t*)((char*)ws + WS_U_B);
  int bkey = b & 7;
  int pos = (((lane >> 3) ^ bkey) & 7)*8 + (lane & 7);

  int lv0 = (w * 125) >> 2;                         // uniform bounds (SGPR)
  int lv1 = ((w + 1) * 125) >> 2;
  #pragma unroll 4
  for (int lv = lv0; lv < lv1; ++lv) {
    float xv = smem[lv * 64 + lane];                // stride-1: conflict-free
    int v = vbase + lv;                             // uniform -> s_load ne
    Ux[(size_t)v*12288 + b*64 + pos] = (uint16_t)f2bf(xv);  // U[c=0]
    #pragma unroll
    for (int d = 0; d < DD; ++d) {
      zr[d] += ne_re[v*DD + d] * xv;
      zi[d] -= ne_im[v*DD + d] * xv;
    }
  }
  __syncthreads();                                  // all waves done with x-tile

  #pragma unroll
  for (int d = 0; d < DD; ++d) {
    smem[w*2048 + d*128 + lane*2 + 0] = zr[d];
    smem[w*2048 + d*128 + lane*2 + 1] = zi[d];
  }
  __syncthreads();
  float* ZP = ws + WS_ZP_DW;
  #pragma unroll
  for (int k = 0; k < 8; ++k) {
    int j = t + k*256;
    float s = smem[j] + smem[2048 + j] + smem[4096 + j] + smem[6144 + j];
    int d = j >> 7, r = j & 127;
    ZP[(size_t)c*131072 + d*8192 + b*128 + r] = s;
  }
}

// ne: NE[u][col] bf16, col = h*32 + d*2 + p; h=0: bf16(ne), h=1: bf16(ne - hi)
__device__ __forceinline__ void body_ne(int bx, int t,
    const float* __restrict__ ne_re, const float* __restrict__ ne_im,
    float* __restrict__ ws) {
  int gid = bx * 256 + t;                     // 512 blocks -> 131072
  int u = gid >> 6, col = gid & 63;
  int h = col >> 5, kk = col & 31, d = kk >> 1, p = kk & 1;
  float v = 0.f;
  if (u < VV) v = p ? ne_im[u*DD + d] : ne_re[u*DD + d];
  uint32_t hi = f2bf(v);
  uint32_t ov = h ? f2bf(v - __uint_as_float(hi << 16)) : hi;
  ((uint16_t*)((char*)ws + WS_NE_B))[gid] = (uint16_t)ov;
}

// rhs: compact RHS[n'][k]. 256 blocks = (c:4)x(ig4:16)x(dq:4).
__device__ __forceinline__ void body_rhs(int bx, int t,
    const float* __restrict__ w_re, const float* __restrict__ w_im,
    float* __restrict__ ws) {
  int c = bx >> 6, sub = bx & 63;
  int ig4 = sub & 15, dq = sub >> 4;
  int o = t & 63, il = t >> 6;
  int i = ig4*4 + il;
  int cb = c >> 1;                     // 0: wA = w0-w2, 1: wB = w1+2w2
  int imf = c & 1;                     // odd comp: (Im, Re); even: (Re, -Im)

  uint32_t row32[4];
  #pragma unroll
  for (int d4 = 0; d4 < 4; ++d4) {
    int d = dq*4 + d4;
    int b0 = (d*192 + i)*64 + o;       // w[d,kc,i,o]: d stride 12288, kc 4096
    float vre, vim;
    if (cb == 0) {
      vre = w_re[b0] - w_re[b0 + 8192];
      vim = w_im[b0] - w_im[b0 + 8192];
    } else {
      vre = w_re[b0 + 4096] + 2.f*w_re[b0 + 8192];
      vim = w_im[b0 + 4096] + 2.f*w_im[b0 + 8192];
    }
    float q0 = imf ? vim : vre;
    float q1 = imf ? vre : -vim;
    row32[d4] = f2bf(q0) | (f2bf(q1) << 16);
  }
  int s = ((i >> 3) ^ (o & 7)) & 7;
  int n = c*4096 + o*64 + s*8 + (i & 7);
  uint4* dst = (uint4*)((uint16_t*)((char*)ws + WS_RHS_B) + (size_t)n*64);
  uint4 qv = make_uint4(row32[0], row32[1], row32[2], row32[3]);
  dst[dq]     = qv;   // h=0
  dst[dq + 4] = qv;   // h=1 duplicate (hi/lo ne split reconstructs fp32)
}

// norm1: partial Gram. 100 virtual blocks x 20 v. Partials to NP.
__device__ __forceinline__ void body_norm1(int bx, int t,
    const float* __restrict__ ne_re, const float* __restrict__ ne_im,
    float* __restrict__ ws) {
  int d = t >> 4, e = t & 15;
  int v0 = bx * 20;
  float gr = 0.f, gi = 0.f;
  #pragma unroll 4
  for (int v = v0; v < v0 + 20; ++v) {
    float ar = ne_re[v*DD + d], ai = ne_im[v*DD + d];
    float br = ne_re[v*DD + e], bi = ne_im[v*DD + e];
    gr += ar*br + ai*bi;
    gi += ar*bi - ai*br;
  }
  float* NP = ws + WS_NP_DW;
  NP[bx*512 + 2*t]     = gr;
  NP[bx*512 + 2*t + 1] = gi;
}

// bias: bias2[u][2*o+half] fp32 (interleaved so k_final stores are linear)
__device__ __forceinline__ void body_bias(int bx, int t,
    const float* __restrict__ ne_re, const float* __restrict__ ne_im,
    const float* __restrict__ b_re, const float* __restrict__ b_im,
    float* __restrict__ ws) {
  int gid = bx * 256 + t;                     // 1000 blocks -> 256000
  int u = gid >> 7, idx = gid & 127;
  int o = idx >> 1, half = idx & 1;
  float acc = 0.f;
  #pragma unroll
  for (int d = 0; d < DD; ++d) {
    float nr = ne_re[u*DD + d], ni = ne_im[u*DD + d];
    float pr = b_re[d*CO + o],  pi = b_im[d*CO + o];
    acc += half ? (nr*pi + ni*pr) : (nr*pr - ni*pi);
  }
  ws[WS_BIAS_DW + gid] = acc;
}

// wgemm: W GEMM -> compact Wc[u][16384].
__device__ __forceinline__ void body_wgemm(int bx, int t, float* __restrict__ ws) {
  const uint16_t* NE  = (const uint16_t*)((char*)ws + WS_NE_B);
  const uint16_t* RHS = (const uint16_t*)((char*)ws + WS_RHS_B);
  uint32_t*       W   = (uint32_t*)((char*)ws + WS_W_B);
  int ut = bx & 31, nc = bx >> 5;
  int w = t >> 6, lane = t & 63;
  int n16 = lane & 15, quad = lane >> 4;
  short8 a[4][2];
  #pragma unroll
  for (int m = 0; m < 4; ++m) {
    int u = ut*64 + m*16 + n16;
    a[m][0] = *(const short8*)(NE + u*64 + quad*8);
    a[m][1] = *(const short8*)(NE + u*64 + 32 + quad*8);
  }
  int nbase = nc*1024 + w*256;
  #pragma unroll 2
  for (int pt = 0; pt < 8; ++pt) {
    int nb = nbase + pt*32;
    const uint16_t* r0 = RHS + (size_t)(nb + 2*n16 + 0)*64 + quad*8;
    const uint16_t* r1 = RHS + (size_t)(nb + 2*n16 + 1)*64 + quad*8;
    short8 b00 = *(const short8*)r0;
    short8 b01 = *(const short8*)(r0 + 32);
    short8 b10 = *(const short8*)r1;
    short8 b11 = *(const short8*)(r1 + 32);
    #pragma unroll
    for (int m = 0; m < 4; ++m) {
      f32x4 acc0 = (f32x4){0.f,0.f,0.f,0.f};
      f32x4 acc1 = (f32x4){0.f,0.f,0.f,0.f};
      acc0 = __builtin_amdgcn_mfma_f32_16x16x32_bf16(a[m][0], b00, acc0, 0, 0, 0);
      acc0 = __builtin_amdgcn_mfma_f32_16x16x32_bf16(a[m][1], b01, acc0, 0, 0, 0);
      acc1 = __builtin_amdgcn_mfma_f32_16x16x32_bf16(a[m][0], b10, acc1, 0, 0, 0);
      acc1 = __builtin_amdgcn_mfma_f32_16x16x32_bf16(a[m][1], b11, acc1, 0, 0, 0);
      #pragma unroll
      for (int r = 0; r < 4; ++r) {
        int u = ut*64 + m*16 + quad*4 + r;
        if (u < VV) {
          uint32_t pk = f2bf(acc0[r]) | (f2bf(acc1[r]) << 16);
          W[(size_t)u*8192 + (nb >> 1) + n16] = pk;
        }
      }
    }
  }
}

// zred: Z = sum over 16 chunks of ZP. 256 virtual blocks.
__device__ __forceinline__ void body_zred(int bx, int t, float* __restrict__ ws) {
  int g = bx * 256 + t;
  const float2* ZP2 = (const float2*)(ws + WS_ZP_DW);
  float2 acc = make_float2(0.f, 0.f);
  #pragma unroll
  for (int c = 0; c < 16; ++c) {
    float2 v = ZP2[(size_t)c*65536 + g];
    acc.x += v.x; acc.y += v.y;
  }
  ((float2*)(ws + WS_Z_DW))[g] = acc;
}

// norm2: reduce NP partials -> INV. 1 virtual block. 100 partials.
__device__ __forceinline__ void body_norm2(int t, float* __restrict__ ws) {
  const float* NP = ws + WS_NP_DW;
  float gr = 0.f, gi = 0.f;
  #pragma unroll
  for (int p = 0; p < 100; ++p) {
    gr += NP[p*512 + 2*t];
    gi += NP[p*512 + 2*t + 1];
  }
  __shared__ float red[256];
  red[t] = gr*gr + gi*gi;
  __syncthreads();
  for (int k = 128; k > 0; k >>= 1) {
    if (t < k) red[t] += red[t + k];
    __syncthreads();
  }
  if (t == 0) ws[WS_INV_DW] = 1.0f / sqrtf(red[0]);
}

// ---------------------------------------------------------------------------
// Fused dispatchers
// ---------------------------------------------------------------------------

// k_front: 2892 blocks, longest-per-block first:
//   z [0,1024) | rhs [1024,1280) | norm1 [1280,1380) |
//   bias [1380,2380) | ne [2380,2892)
__global__ void __launch_bounds__(256, 4)
k_front(const float* __restrict__ x, const float* __restrict__ ne_re,
        const float* __restrict__ ne_im, const float* __restrict__ w_re,
        const float* __restrict__ w_im, const float* __restrict__ b_re,
        const float* __restrict__ b_im, float* __restrict__ ws) {
  int bx = blockIdx.x, t = threadIdx.x;
  if (bx < 1024) {
    body_z(bx, t, x, ne_re, ne_im, ws);
  } else if (bx < 1280) {
    body_rhs(bx - 1024, t, w_re, w_im, ws);
  } else if (bx < 1380) {
    body_norm1(bx - 1280, t, ne_re, ne_im, ws);
  } else if (bx < 2380) {
    body_bias(bx - 1380, t, ne_re, ne_im, b_re, b_im, ws);
  } else {
    body_ne(bx - 2380, t, ne_re, ne_im, ws);
  }
}

// k_mid: 769 blocks. wgemm [0,512) | zred [512,768) | norm2 768.
__global__ void __launch_bounds__(256, 4)
k_mid(float* __restrict__ ws) {
  int bx = blockIdx.x, t = threadIdx.x;
  if (bx < 512) {
    body_wgemm(bx, t, ws);
  } else if (bx < 768) {
    body_zred(bx - 512, t, ws);
  } else {
    body_norm2(t, ws);
  }
}

// K7: y-only. compact U[u][1,2][64][64] (yr, yi; swizzle baked).
__global__ void __launch_bounds__(256, 4)
k_u(const float* __restrict__ x, const float* __restrict__ ne_re,
    const float* __restrict__ ne_im, float* __restrict__ ws) {
  (void)x;
  int ug = blockIdx.x, by = blockIdx.y;
  int t = threadIdx.x, q = t >> 6, i = t & 63;
  int b = by*4 + q;
  float invn = ws[WS_INV_DW];

  // Z loads (16 x 8B, cache-resident)
  const float* Z = ws + WS_Z_DW;
  float zr[DD], zi[DD];
  #pragma unroll
  for (int d = 0; d < DD; ++d) {
    const float* zp = Z + (size_t)(d*4096 + b*64 + i) * 2;
    zr[d] = zp[0]; zi[d] = zp[1];
  }

  __shared__ uint16_t sStage[128 * 64];       // rr = ul*8 + cc*4 + q
  int bkey = b & 7;
  int pos = (((i >> 3) ^ bkey) & 7)*8 + (i & 7);

  // y compute, fully unrolled, split accumulators
  #pragma unroll
  for (int ul = 0; ul < 16; ++ul) {
    int u = ug*16 + ul;
    float yra = 0.f, yrb = 0.f, yia = 0.f, yib = 0.f;
    #pragma unroll
    for (int d = 0; d < DD; ++d) {
      float nr = ne_re[u*DD + d], ni = ne_im[u*DD + d];
      yra += nr*zr[d]; yrb += ni*zi[d];
      yia += nr*zi[d]; yib += ni*zr[d];
    }
    float yr = yra - yrb, yi = yia + yib;
    sStage[(ul*8 + 0 + q)*64 + pos] = (uint16_t)f2bf(yr * invn);
    sStage[(ul*8 + 4 + q)*64 + pos] = (uint16_t)f2bf(yi * invn);
  }
  __syncthreads();
  // flush: 128 rows x 128B, 32 rows per pass (8 lanes/row), 4 passes
  uint16_t* U = (uint16_t*)((char*)ws + WS_U_B);
  const uint4* sv = (const uint4*)sStage;
  #pragma unroll
  for (int pass = 0; pass < 4; ++pass) {
    int rr = pass*32 + (t >> 3), l8 = t & 7;
    int ul = rr >> 3, rem = rr & 7;
    int cc = rem >> 2, qq = rem & 3;             // cc: 0=yr->c=1, 1=yi->c=2
    uint4 v = sv[rr*8 + l8];
    *(uint4*)(U + (size_t)(ug*16 + ul)*12288 + (1+cc)*4096 + (by*4 + qq)*64 + l8*8) = v;
  }
}

// K8: per-node MFMA from compact W,U.
// R15: two-phase LDS (40 KB instead of 70 KB) -> more blocks/CU.
// R17 fix: launch_bounds (512,6) -> (512,3). The 6-waves/EU demand squeezed
// the allocator to VGPR_Count=20, spilling the 7x16B prefetch + accumulators
// to scratch: WRITE_SIZE ballooned 66->176 MB (2000 blk x 512 thr x 112 B
// round trip) and k_final hit 58 us. Cap 512/3=170 VGPRs: no spill; occupancy
// then LDS-bound at 4 blocks/CU (40 KB each), still 2x the old 70 KB kernel.
// Phase partition (validated passed=true in R17):
//   A: W c=0,1 (rows 0..127) + U cb=0 (rows 128..191)       [ks 0,1]
//   B: W c=2,3 (rows 0..127) + U cb=1,2 (rows 128..255)     [ks 2..5]
#define LP 80           // LDS row pitch (elems)
#define CSTRIDE 5120    // 64*LP: comp stride (elems)
__global__ void __launch_bounds__(512, 3)
k_final(const float* __restrict__ ws, float* __restrict__ out) {
  int u = blockIdx.x, t = threadIdx.x;
  __shared__ __align__(16) uint16_t sB[256 * LP];      // 40960 B, dual-phase
  const uint4* Wg = (const uint4*)((const char*)ws + WS_W_B + (size_t)u*32768);
  const uint4* Ug = (const uint4*)((const char*)ws + WS_U_B + (size_t)u*24576);

  // prefetch all 7 x 16B chunks (independent loads, all in flight)
  uint4 rW[4], rU[3];
  #pragma unroll
  for (int j = 0; j < 4; ++j) rW[j] = Wg[j*512 + t];
  #pragma unroll
  for (int j = 0; j < 3; ++j) rU[j] = Ug[j*512 + t];

  int w = t >> 6, lane = t & 63;
  int n16 = lane & 15, quad = lane >> 4;
  int o = w*8 + (n16 >> 1), half = n16 & 1;
  int okey = o & 7;
  uint32_t sgnmask = half ? 0u : 0x80008000u;  // negate Bi for re-half at cb=2
  f32x4 acc[4];
  #pragma unroll
  for (int m = 0; m < 4; ++m) acc[m] = (f32x4){0.f,0.f,0.f,0.f};

  // ---- Phase A stage: W c=0,1 -> rows 0..127; U cb=0 -> rows 128..191 ----
  #pragma unroll
  for (int j = 0; j < 2; ++j) {
    int idx = j*512 + t;                       // rows 0..127
    *(uint4*)&sB[(idx >> 3)*LP + (idx & 7)*8] = rW[j];
  }
  {
    int idx = t;                               // U rows 0..63 -> LDS 128..191
    *(uint4*)&sB[(128 + (idx >> 3))*LP + (idx & 7)*8] = rU[0];
  }
  __syncthreads();

  // ---- Phase A compute: ks = 0,1 (cb=0, c=half) ----
  #pragma unroll
  for (int ks = 0; ks < 2; ++ks) {
    int i8 = ks*4 + quad;
    int c  = half;
    int slot = (i8 ^ okey) & 7;
    short8 bfrag = *(const short8*)&sB[c*CSTRIDE + o*LP + slot*8];
    #pragma unroll
    for (int m = 0; m < 4; ++m) {
      int b = m*16 + n16;
      int aslot = (i8 ^ (b & 7)) & 7;
      short8 afrag = *(const short8*)&sB[(128 + b)*LP + aslot*8];
      acc[m] = __builtin_amdgcn_mfma_f32_16x16x32_bf16(afrag, bfrag, acc[m], 0, 0, 0);
    }
  }
  __syncthreads();

  // ---- Phase B stage: W c=2,3 -> rows 0..127; U cb=1,2 -> rows 128..255 ----
  #pragma unroll
  for (int j = 2; j < 4; ++j) {
    int idx = j*512 + t;
    int row = (idx >> 3) - 128;                // c=2,3 -> rows 0..127
    *(uint4*)&sB[row*LP + (idx & 7)*8] = rW[j];
  }
  #pragma unroll
  for (int j = 1; j < 3; ++j) {
    int idx = j*512 + t;
    int row = (idx >> 3) - 64;                 // cb=1,2 -> rows 0..127
    *(uint4*)&sB[(128 + row)*LP + (idx & 7)*8] = rU[j];
  }
  __syncthreads();

  // ---- Phase B compute: ks = 2..5 (cb=1,2) ----
  #pragma unroll
  for (int ks = 2; ks < 6; ++ks) {
    int cb = ks >> 1;                          // 1,1,2,2
    int i8 = (ks & 1)*4 + quad;
    int c  = (cb == 1) ? 2 + half : 3 - half;  // in {2,3}
    int c2 = c - 2;
    int slot = (i8 ^ okey) & 7;
    short8 bfrag = *(const short8*)&sB[c2*CSTRIDE + o*LP + slot*8];
    if (cb == 2) {
      uint32_t* bu = (uint32_t*)&bfrag;
      #pragma unroll
      for (int jj = 0; jj < 4; ++jj) bu[jj] ^= sgnmask;
    }
    int cbl = cb - 1;                          // 0,1
    #pragma unroll
    for (int m = 0; m < 4; ++m) {
      int b = m*16 + n16;
      int aslot = (i8 ^ (b & 7)) & 7;
      short8 afrag = *(const short8*)&sB[(128 + cbl*64 + b)*LP + aslot*8];
      acc[m] = __builtin_amdgcn_mfma_f32_16x16x32_bf16(afrag, bfrag, acc[m], 0, 0, 0);
    }
  }

  float bias = ws[WS_BIAS_DW + u*128 + w*16 + n16];
  #pragma unroll
  for (int m = 0; m < 4; ++m) {
    #pragma unroll
    for (int r = 0; r < 4; ++r) {
      int b = m*16 + quad*4 + r;
      out[((size_t)b*VV + u)*128 + w*16 + n16] = acc[m][r] + bias;
    }
  }
}

// ---------------------------------------------------------------------------
extern "C" void kernel_launch(void* const* d_in, const int* in_sizes, int n_in,
                              void* d_out, int out_size, void* d_ws, size_t ws_size,
                              hipStream_t stream) {
  (void)in_sizes; (void)n_in; (void)out_size; (void)ws_size;
  const float* x     = (const float*)d_in[0];
  const float* ne_re = (const float*)d_in[1];
  const float* ne_im = (const float*)d_in[2];
  const float* w_re  = (const float*)d_in[3];
  const float* w_im  = (const float*)d_in[4];
  const float* b_re  = (const float*)d_in[5];
  const float* b_im  = (const float*)d_in[6];
  float* out = (float*)d_out;
  float* ws  = (float*)d_ws;

  k_front<<<dim3(2892),    dim3(256), 0, stream>>>(x, ne_re, ne_im, w_re, w_im,
                                                   b_re, b_im, ws);
  k_mid  <<<dim3(769),     dim3(256), 0, stream>>>(ws);
  k_u    <<<dim3(125, 16), dim3(256), 0, stream>>>(x, ne_re, ne_im, ws);
  k_final<<<dim3(VV),      dim3(512), 0, stream>>>(ws, out);
}

// Round 21
// 181.470 us; speedup vs baseline: 1.2279x; 1.2228x over previous
//
#include <hip/hip_runtime.h>
#include <stdint.h>

// Problem constants
#define BB 64
#define VV 2000
#define DD 16
#define CI 64
#define CO 64

// ---- ws layout ----
// dword offsets (fp32 region)
#define WS_INV_DW   0
#define WS_Z_DW     1024                    // float2[16][4096]
#define WS_BIAS_DW  132096                  // fp32 [2000][128]  (idx = 2*o+half)
// byte offsets (bf16 regions), all 16B-aligned
#define WS_NE_B     1552384UL               // bf16 [2048][64]  (hi/lo split ne)
#define WS_RHS_B    1814528UL               // bf16 [16384][64] compact RHS
#define WS_U_B      4960256UL               // bf16 [2000][3][64][64] compact U
#define WS_W_B      54112256UL              // bf16 [2000][4][64][64] compact W
// R8: ZP (z partials) and NP (norm1 partials) in DEDICATED space at 128 MiB.
#define WS_ZP_DW    33554432                // byte 128 MiB; 8.4 MB
#define WS_NP_DW    (WS_ZP_DW + 2097152)    // 100 blocks x 512 floats

typedef __attribute__((ext_vector_type(8))) short short8;
typedef __attribute__((ext_vector_type(4))) float f32x4;

__device__ __forceinline__ uint32_t f2bf(float f) {
  uint32_t u = __float_as_uint(f);
  return (u + 0x7FFFu + ((u >> 16) & 1u)) >> 16;   // RNE
}

// Direct global->LDS DMA, 16B per lane. LDS dest = wave-uniform base +
// lane*16; global src is per-lane. No VGPR round trip, no scratch.
__device__ __forceinline__ void gload_lds16(const void* g, void* l) {
  __builtin_amdgcn_global_load_lds(
      (const __attribute__((address_space(1))) uint32_t*)g,
      (__attribute__((address_space(3))) uint32_t*)l, 16, 0, 0);
}

// ---------------------------------------------------------------------------
// Component bodies, fused into k_front / k_mid by blockIdx range.
//   k_front: {z (+U[c=0] write), rhs, norm1, bias, ne}   (independent)
//   k_mid:   {wgemm, zred, norm2}        (all need only k_front)
//   k_u:     needs Z + INV (k_mid); writes U[c=1,2] only
//   k_final: needs W (k_mid) + U (k_front c=0, k_u c=1,2) + bias (k_front)
// ---------------------------------------------------------------------------

// z: Z partials. 1024 virtual blocks = (b:64)x(chunk:16).
__device__ __forceinline__ void body_z(int bz, int t,
    const float* __restrict__ x, const float* __restrict__ ne_re,
    const float* __restrict__ ne_im, float* __restrict__ ws) {
  int b = bz >> 4, c = bz & 15;
  int lane = t & 63;
  int w = __builtin_amdgcn_readfirstlane(t >> 6);   // wave-uniform in SGPR
  __shared__ __align__(16) float smem[8192];        // 32 KB: x-tile, then sred

  int vbase = c * 125;

  // stage x[b, vbase..vbase+125, :] = 32000 B contiguous into LDS via DMA.
  {
    const float4* xg = (const float4*)(x + ((size_t)b * VV + vbase) * CI);
    int wb = t & 192;                               // w*64, uniform per wave
    #pragma unroll
    for (int p = 0; p < 8; ++p) {
      int idx = p * 256 + t;
      if (idx < 2000)
        gload_lds16(xg + idx, &smem[(p * 256 + wb) * 4]);
    }
  }
  __syncthreads();                                  // compiler drains vmcnt

  float zr[DD], zi[DD];
  #pragma unroll
  for (int d = 0; d < DD; ++d) { zr[d] = 0.f; zi[d] = 0.f; }

  uint16_t* Ux = (uint16_t*)((char*)ws + WS_U_B);
  int bkey = b & 7;
  int pos = (((lane >> 3) ^ bkey) & 7)*8 + (lane & 7);

  int lv0 = (w * 125) >> 2;                         // uniform bounds (SGPR)
  int lv1 = ((w + 1) * 125) >> 2;
  #pragma unroll 4
  for (int lv = lv0; lv < lv1; ++lv) {
    float xv = smem[lv * 64 + lane];                // stride-1: conflict-free
    int v = vbase + lv;                             // uniform -> s_load ne
    Ux[(size_t)v*12288 + b*64 + pos] = (uint16_t)f2bf(xv);  // U[c=0]
    #pragma unroll
    for (int d = 0; d < DD; ++d) {
      zr[d] += ne_re[v*DD + d] * xv;
      zi[d] -= ne_im[v*DD + d] * xv;
    }
  }
  __syncthreads();                                  // all waves done with x-tile

  #pragma unroll
  for (int d = 0; d < DD; ++d) {
    smem[w*2048 + d*128 + lane*2 + 0] = zr[d];
    smem[w*2048 + d*128 + lane*2 + 1] = zi[d];
  }
  __syncthreads();
  float* ZP = ws + WS_ZP_DW;
  #pragma unroll
  for (int k = 0; k < 8; ++k) {
    int j = t + k*256;
    float s = smem[j] + smem[2048 + j] + smem[4096 + j] + smem[6144 + j];
    int d = j >> 7, r = j & 127;
    ZP[(size_t)c*131072 + d*8192 + b*128 + r] = s;
  }
}

// ne: NE[u][col] bf16, col = h*32 + d*2 + p; h=0: bf16(ne), h=1: bf16(ne - hi)
__device__ __forceinline__ void body_ne(int bx, int t,
    const float* __restrict__ ne_re, const float* __restrict__ ne_im,
    float* __restrict__ ws) {
  int gid = bx * 256 + t;                     // 512 blocks -> 131072
  int u = gid >> 6, col = gid & 63;
  int h = col >> 5, kk = col & 31, d = kk >> 1, p = kk & 1;
  float v = 0.f;
  if (u < VV) v = p ? ne_im[u*DD + d] : ne_re[u*DD + d];
  uint32_t hi = f2bf(v);
  uint32_t ov = h ? f2bf(v - __uint_as_float(hi << 16)) : hi;
  ((uint16_t*)((char*)ws + WS_NE_B))[gid] = (uint16_t)ov;
}

// rhs: compact RHS[n'][k]. 256 blocks = (c:4)x(ig4:16)x(dq:4).
__device__ __forceinline__ void body_rhs(int bx, int t,
    const float* __restrict__ w_re, const float* __restrict__ w_im,
    float* __restrict__ ws) {
  int c = bx >> 6, sub = bx & 63;
  int ig4 = sub & 15, dq = sub >> 4;
  int o = t & 63, il = t >> 6;
  int i = ig4*4 + il;
  int cb = c >> 1;                     // 0: wA = w0-w2, 1: wB = w1+2w2
  int imf = c & 1;                     // odd comp: (Im, Re); even: (Re, -Im)

  uint32_t row32[4];
  #pragma unroll
  for (int d4 = 0; d4 < 4; ++d4) {
    int d = dq*4 + d4;
    int b0 = (d*192 + i)*64 + o;       // w[d,kc,i,o]: d stride 12288, kc 4096
    float vre, vim;
    if (cb == 0) {
      vre = w_re[b0] - w_re[b0 + 8192];
      vim = w_im[b0] - w_im[b0 + 8192];
    } else {
      vre = w_re[b0 + 4096] + 2.f*w_re[b0 + 8192];
      vim = w_im[b0 + 4096] + 2.f*w_im[b0 + 8192];
    }
    float q0 = imf ? vim : vre;
    float q1 = imf ? vre : -vim;
    row32[d4] = f2bf(q0) | (f2bf(q1) << 16);
  }
  int s = ((i >> 3) ^ (o & 7)) & 7;
  int n = c*4096 + o*64 + s*8 + (i & 7);
  uint4* dst = (uint4*)((uint16_t*)((char*)ws + WS_RHS_B) + (size_t)n*64);
  uint4 qv = make_uint4(row32[0], row32[1], row32[2], row32[3]);
  dst[dq]     = qv;   // h=0
  dst[dq + 4] = qv;   // h=1 duplicate (hi/lo ne split reconstructs fp32)
}

// norm1: partial Gram. 100 virtual blocks x 20 v. Partials to NP.
__device__ __forceinline__ void body_norm1(int bx, int t,
    const float* __restrict__ ne_re, const float* __restrict__ ne_im,
    float* __restrict__ ws) {
  int d = t >> 4, e = t & 15;
  int v0 = bx * 20;
  float gr = 0.f, gi = 0.f;
  #pragma unroll 4
  for (int v = v0; v < v0 + 20; ++v) {
    float ar = ne_re[v*DD + d], ai = ne_im[v*DD + d];
    float br = ne_re[v*DD + e], bi = ne_im[v*DD + e];
    gr += ar*br + ai*bi;
    gi += ar*bi - ai*br;
  }
  float* NP = ws + WS_NP_DW;
  NP[bx*512 + 2*t]     = gr;
  NP[bx*512 + 2*t + 1] = gi;
}

// bias: bias2[u][2*o+half] fp32 (interleaved so k_final stores are linear)
__device__ __forceinline__ void body_bias(int bx, int t,
    const float* __restrict__ ne_re, const float* __restrict__ ne_im,
    const float* __restrict__ b_re, const float* __restrict__ b_im,
    float* __restrict__ ws) {
  int gid = bx * 256 + t;                     // 1000 blocks -> 256000
  int u = gid >> 7, idx = gid & 127;
  int o = idx >> 1, half = idx & 1;
  float acc = 0.f;
  #pragma unroll
  for (int d = 0; d < DD; ++d) {
    float nr = ne_re[u*DD + d], ni = ne_im[u*DD + d];
    float pr = b_re[d*CO + o],  pi = b_im[d*CO + o];
    acc += half ? (nr*pi + ni*pr) : (nr*pr - ni*pi);
  }
  ws[WS_BIAS_DW + gid] = acc;
}

// wgemm: W GEMM -> compact Wc[u][16384].
__device__ __forceinline__ void body_wgemm(int bx, int t, float* __restrict__ ws) {
  const uint16_t* NE  = (const uint16_t*)((char*)ws + WS_NE_B);
  const uint16_t* RHS = (const uint16_t*)((char*)ws + WS_RHS_B);
  uint32_t*       W   = (uint32_t*)((char*)ws + WS_W_B);
  int ut = bx & 31, nc = bx >> 5;
  int w = t >> 6, lane = t & 63;
  int n16 = lane & 15, quad = lane >> 4;
  short8 a[4][2];
  #pragma unroll
  for (int m = 0; m < 4; ++m) {
    int u = ut*64 + m*16 + n16;
    a[m][0] = *(const short8*)(NE + u*64 + quad*8);
    a[m][1] = *(const short8*)(NE + u*64 + 32 + quad*8);
  }
  int nbase = nc*1024 + w*256;
  #pragma unroll 2
  for (int pt = 0; pt < 8; ++pt) {
    int nb = nbase + pt*32;
    const uint16_t* r0 = RHS + (size_t)(nb + 2*n16 + 0)*64 + quad*8;
    const uint16_t* r1 = RHS + (size_t)(nb + 2*n16 + 1)*64 + quad*8;
    short8 b00 = *(const short8*)r0;
    short8 b01 = *(const short8*)(r0 + 32);
    short8 b10 = *(const short8*)r1;
    short8 b11 = *(const short8*)(r1 + 32);
    #pragma unroll
    for (int m = 0; m < 4; ++m) {
      f32x4 acc0 = (f32x4){0.f,0.f,0.f,0.f};
      f32x4 acc1 = (f32x4){0.f,0.f,0.f,0.f};
      acc0 = __builtin_amdgcn_mfma_f32_16x16x32_bf16(a[m][0], b00, acc0, 0, 0, 0);
      acc0 = __builtin_amdgcn_mfma_f32_16x16x32_bf16(a[m][1], b01, acc0, 0, 0, 0);
      acc1 = __builtin_amdgcn_mfma_f32_16x16x32_bf16(a[m][0], b10, acc1, 0, 0, 0);
      acc1 = __builtin_amdgcn_mfma_f32_16x16x32_bf16(a[m][1], b11, acc1, 0, 0, 0);
      #pragma unroll
      for (int r = 0; r < 4; ++r) {
        int u = ut*64 + m*16 + quad*4 + r;
        if (u < VV) {
          uint32_t pk = f2bf(acc0[r]) | (f2bf(acc1[r]) << 16);
          W[(size_t)u*8192 + (nb >> 1) + n16] = pk;
        }
      }
    }
  }
}

// zred: Z = sum over 16 chunks of ZP. 256 virtual blocks.
__device__ __forceinline__ void body_zred(int bx, int t, float* __restrict__ ws) {
  int g = bx * 256 + t;
  const float2* ZP2 = (const float2*)(ws + WS_ZP_DW);
  float2 acc = make_float2(0.f, 0.f);
  #pragma unroll
  for (int c = 0; c < 16; ++c) {
    float2 v = ZP2[(size_t)c*65536 + g];
    acc.x += v.x; acc.y += v.y;
  }
  ((float2*)(ws + WS_Z_DW))[g] = acc;
}

// norm2: reduce NP partials -> INV. 1 virtual block. 100 partials.
__device__ __forceinline__ void body_norm2(int t, float* __restrict__ ws) {
  const float* NP = ws + WS_NP_DW;
  float gr = 0.f, gi = 0.f;
  #pragma unroll
  for (int p = 0; p < 100; ++p) {
    gr += NP[p*512 + 2*t];
    gi += NP[p*512 + 2*t + 1];
  }
  __shared__ float red[256];
  red[t] = gr*gr + gi*gi;
  __syncthreads();
  for (int k = 128; k > 0; k >>= 1) {
    if (t < k) red[t] += red[t + k];
    __syncthreads();
  }
  if (t == 0) ws[WS_INV_DW] = 1.0f / sqrtf(red[0]);
}

// ---------------------------------------------------------------------------
// Fused dispatchers
// ---------------------------------------------------------------------------

// k_front: 2892 blocks, longest-per-block first:
//   z [0,1024) | rhs [1024,1280) | norm1 [1280,1380) |
//   bias [1380,2380) | ne [2380,2892)
__global__ void __launch_bounds__(256, 4)
k_front(const float* __restrict__ x, const float* __restrict__ ne_re,
        const float* __restrict__ ne_im, const float* __restrict__ w_re,
        const float* __restrict__ w_im, const float* __restrict__ b_re,
        const float* __restrict__ b_im, float* __restrict__ ws) {
  int bx = blockIdx.x, t = threadIdx.x;
  if (bx < 1024) {
    body_z(bx, t, x, ne_re, ne_im, ws);
  } else if (bx < 1280) {
    body_rhs(bx - 1024, t, w_re, w_im, ws);
  } else if (bx < 1380) {
    body_norm1(bx - 1280, t, ne_re, ne_im, ws);
  } else if (bx < 2380) {
    body_bias(bx - 1380, t, ne_re, ne_im, b_re, b_im, ws);
  } else {
    body_ne(bx - 2380, t, ne_re, ne_im, ws);
  }
}

// k_mid: 769 blocks. wgemm [0,512) | zred [512,768) | norm2 768.
__global__ void __launch_bounds__(256, 4)
k_mid(float* __restrict__ ws) {
  int bx = blockIdx.x, t = threadIdx.x;
  if (bx < 512) {
    body_wgemm(bx, t, ws);
  } else if (bx < 768) {
    body_zred(bx - 512, t, ws);
  } else {
    body_norm2(t, ws);
  }
}

// K7: y-only. compact U[u][1,2][64][64] (yr, yi; swizzle baked).
__global__ void __launch_bounds__(256, 4)
k_u(const float* __restrict__ x, const float* __restrict__ ne_re,
    const float* __restrict__ ne_im, float* __restrict__ ws) {
  (void)x;
  int ug = blockIdx.x, by = blockIdx.y;
  int t = threadIdx.x, q = t >> 6, i = t & 63;
  int b = by*4 + q;
  float invn = ws[WS_INV_DW];

  // Z loads (16 x 8B, cache-resident)
  const float* Z = ws + WS_Z_DW;
  float zr[DD], zi[DD];
  #pragma unroll
  for (int d = 0; d < DD; ++d) {
    const float* zp = Z + (size_t)(d*4096 + b*64 + i) * 2;
    zr[d] = zp[0]; zi[d] = zp[1];
  }

  __shared__ uint16_t sStage[128 * 64];       // rr = ul*8 + cc*4 + q
  int bkey = b & 7;
  int pos = (((i >> 3) ^ bkey) & 7)*8 + (i & 7);

  // y compute, fully unrolled, split accumulators
  #pragma unroll
  for (int ul = 0; ul < 16; ++ul) {
    int u = ug*16 + ul;
    float yra = 0.f, yrb = 0.f, yia = 0.f, yib = 0.f;
    #pragma unroll
    for (int d = 0; d < DD; ++d) {
      float nr = ne_re[u*DD + d], ni = ne_im[u*DD + d];
      yra += nr*zr[d]; yrb += ni*zi[d];
      yia += nr*zi[d]; yib += ni*zr[d];
    }
    float yr = yra - yrb, yi = yia + yib;
    sStage[(ul*8 + 0 + q)*64 + pos] = (uint16_t)f2bf(yr * invn);
    sStage[(ul*8 + 4 + q)*64 + pos] = (uint16_t)f2bf(yi * invn);
  }
  __syncthreads();
  // flush: 128 rows x 128B, 32 rows per pass (8 lanes/row), 4 passes
  uint16_t* U = (uint16_t*)((char*)ws + WS_U_B);
  const uint4* sv = (const uint4*)sStage;
  #pragma unroll
  for (int pass = 0; pass < 4; ++pass) {
    int rr = pass*32 + (t >> 3), l8 = t & 7;
    int ul = rr >> 3, rem = rr & 7;
    int cc = rem >> 2, qq = rem & 3;             // cc: 0=yr->c=1, 1=yi->c=2
    uint4 v = sv[rr*8 + l8];
    *(uint4*)(U + (size_t)(ug*16 + ul)*12288 + (1+cc)*4096 + (by*4 + qq)*64 + l8*8) = v;
  }
}

// K8: per-node MFMA from compact W,U.
// R20 diagnosis: the reg-prefetch (rW/rU) lived across barriers -> compiler
// spilled it to scratch REGARDLESS of launch_bounds budget ((512,6) and
// (512,3) both gave VGPR_Count=20, WRITE 176 MB). Fix: load global->LDS
// DIRECTLY inside each phase (values short-lived, like the R8 version that
// never spilled). Two-phase 40 KB LDS layout kept (validated passed=true
// twice); launch_bounds restored to the known-good (512,2).
//   A: W c=0,1 (rows 0..127) + U cb=0 (rows 128..191)       [ks 0,1]
//   B: W c=2,3 (rows 0..127) + U cb=1,2 (rows 128..255)     [ks 2..5]
#define LP 80           // LDS row pitch (elems)
#define CSTRIDE 5120    // 64*LP: comp stride (elems)
__global__ void __launch_bounds__(512, 2)
k_final(const float* __restrict__ ws, float* __restrict__ out) {
  int u = blockIdx.x, t = threadIdx.x;
  __shared__ __align__(16) uint16_t sB[256 * LP];      // 40960 B, dual-phase
  const uint4* Wg = (const uint4*)((const char*)ws + WS_W_B + (size_t)u*32768);
  const uint4* Ug = (const uint4*)((const char*)ws + WS_U_B + (size_t)u*24576);

  int w = t >> 6, lane = t & 63;
  int n16 = lane & 15, quad = lane >> 4;
  int o = w*8 + (n16 >> 1), half = n16 & 1;
  int okey = o & 7;
  uint32_t sgnmask = half ? 0u : 0x80008000u;  // negate Bi for re-half at cb=2
  f32x4 acc[4];
  #pragma unroll
  for (int m = 0; m < 4; ++m) acc[m] = (f32x4){0.f,0.f,0.f,0.f};

  // ---- Phase A stage (direct): W c=0,1 -> rows 0..127; U cb=0 -> 128..191 --
  #pragma unroll
  for (int j = 0; j < 2; ++j) {
    int idx = j*512 + t;                       // rows 0..127
    *(uint4*)&sB[(idx >> 3)*LP + (idx & 7)*8] = Wg[idx];
  }
  {
    int idx = t;                               // U rows 0..63 -> LDS 128..191
    *(uint4*)&sB[(128 + (idx >> 3))*LP + (idx & 7)*8] = Ug[idx];
  }
  __syncthreads();

  // ---- Phase A compute: ks = 0,1 (cb=0, c=half) ----
  #pragma unroll
  for (int ks = 0; ks < 2; ++ks) {
    int i8 = ks*4 + quad;
    int c  = half;
    int slot = (i8 ^ okey) & 7;
    short8 bfrag = *(const short8*)&sB[c*CSTRIDE + o*LP + slot*8];
    #pragma unroll
    for (int m = 0; m < 4; ++m) {
      int b = m*16 + n16;
      int aslot = (i8 ^ (b & 7)) & 7;
      short8 afrag = *(const short8*)&sB[(128 + b)*LP + aslot*8];
      acc[m] = __builtin_amdgcn_mfma_f32_16x16x32_bf16(afrag, bfrag, acc[m], 0, 0, 0);
    }
  }
  __syncthreads();

  // ---- Phase B stage (direct): W c=2,3 -> rows 0..127; U cb=1,2 -> 128..255
  #pragma unroll
  for (int j = 2; j < 4; ++j) {
    int idx = j*512 + t;
    int row = (idx >> 3) - 128;                // c=2,3 -> rows 0..127
    *(uint4*)&sB[row*LP + (idx & 7)*8] = Wg[idx];
  }
  #pragma unroll
  for (int j = 1; j < 3; ++j) {
    int idx = j*512 + t;
    int row = (idx >> 3) - 64;                 // cb=1,2 -> rows 0..127
    *(uint4*)&sB[(128 + row)*LP + (idx & 7)*8] = Ug[idx];
  }
  __syncthreads();

  // ---- Phase B compute: ks = 2..5 (cb=1,2) ----
  #pragma unroll
  for (int ks = 2; ks < 6; ++ks) {
    int cb = ks >> 1;                          // 1,1,2,2
    int i8 = (ks & 1)*4 + quad;
    int c  = (cb == 1) ? 2 + half : 3 - half;  // in {2,3}
    int c2 = c - 2;
    int slot = (i8 ^ okey) & 7;
    short8 bfrag = *(const short8*)&sB[c2*CSTRIDE + o*LP + slot*8];
    if (cb == 2) {
      uint32_t* bu = (uint32_t*)&bfrag;
      #pragma unroll
      for (int jj = 0; jj < 4; ++jj) bu[jj] ^= sgnmask;
    }
    int cbl = cb - 1;                          // 0,1
    #pragma unroll
    for (int m = 0; m < 4; ++m) {
      int b = m*16 + n16;
      int aslot = (i8 ^ (b & 7)) & 7;
      short8 afrag = *(const short8*)&sB[(128 + cbl*64 + b)*LP + aslot*8];
      acc[m] = __builtin_amdgcn_mfma_f32_16x16x32_bf16(afrag, bfrag, acc[m], 0, 0, 0);
    }
  }

  float bias = ws[WS_BIAS_DW + u*128 + w*16 + n16];
  #pragma unroll
  for (int m = 0; m < 4; ++m) {
    #pragma unroll
    for (int r = 0; r < 4; ++r) {
      int b = m*16 + quad*4 + r;
      out[((size_t)b*VV + u)*128 + w*16 + n16] = acc[m][r] + bias;
    }
  }
}

// ---------------------------------------------------------------------------
extern "C" void kernel_launch(void* const* d_in, const int* in_sizes, int n_in,
                              void* d_out, int out_size, void* d_ws, size_t ws_size,
                              hipStream_t stream) {
  (void)in_sizes; (void)n_in; (void)out_size; (void)ws_size;
  const float* x     = (const float*)d_in[0];
  const float* ne_re = (const float*)d_in[1];
  const float* ne_im = (const float*)d_in[2];
  const float* w_re  = (const float*)d_in[3];
  const float* w_im  = (const float*)d_in[4];
  const float* b_re  = (const float*)d_in[5];
  const float* b_im  = (const float*)d_in[6];
  float* out = (float*)d_out;
  float* ws  = (float*)d_ws;

  k_front<<<dim3(2892),    dim3(256), 0, stream>>>(x, ne_re, ne_im, w_re, w_im,
                                                   b_re, b_im, ws);
  k_mid  <<<dim3(769),     dim3(256), 0, stream>>>(ws);
  k_u    <<<dim3(125, 16), dim3(256), 0, stream>>>(x, ne_re, ne_im, ws);
  k_final<<<dim3(VV),      dim3(512), 0, stream>>>(ws, out);
}